// Round 12
// baseline (191.078 us; speedup 1.0000x reference)
//
#include <hip/hip_runtime.h>

typedef __bf16 bf16_t;
typedef __bf16 bf16x8 __attribute__((ext_vector_type(8)));
typedef float  f32x4  __attribute__((ext_vector_type(4)));
typedef unsigned u32x4 __attribute__((ext_vector_type(4)));

#define MFMA16(a, b, c) __builtin_amdgcn_mfma_f32_16x16x32_bf16((a), (b), (c), 0, 0, 0)

__device__ __forceinline__ float exp2_f(float x) { return __builtin_amdgcn_exp2f(x); }

union BPack { bf16_t h[2]; unsigned u; };

constexpr int Bn = 4, Cc = 128, Nn = 4096, NH = 4, DK = 32;
// fold 1/sqrt(32) * log2(e) into stored Q so MFMA emits exp2-domain logits
constexpr float QSCALE = 0.176776695f * 1.44269504f;

// ---------------------------------------------------------------------------
// K1: fused transpose + QKV projection.
//   v -> vt_s[bh][d][J] transposed; stored value at J is V[p(J)],
//   p(J)=(J&~31)+((J&31)>>1)+((J&1)*16)  (matches MFMA A/B k-slot interleave)
// ---------------------------------------------------------------------------
__global__ __launch_bounds__(256) void k_qkv(const float* __restrict__ x,
                                             const float* __restrict__ Wp,
                                             const float* __restrict__ bp,
                                             bf16_t* __restrict__ q_s,
                                             bf16_t* __restrict__ k_s,
                                             bf16_t* __restrict__ vt_s)
{
    __shared__ __attribute__((aligned(16))) char smem[40960]; // xs 16KB + wp 24KB
    const int n0 = blockIdx.x * 64;
    const int b  = blockIdx.y;
    const int h  = blockIdx.z;
    const int t  = threadIdx.x;
    const int w = t >> 6, lane = t & 63, a = lane & 15, g = lane >> 4;

    const float* xb = x + (size_t)b * Cc * Nn;
    #pragma unroll
    for (int it = 0; it < 16; ++it) {
        int c = ((t >> 6) + it * 4) * 2;
        int n = t & 63;
        BPack p;
        p.h[0] = (bf16_t)xb[(size_t)c * Nn + n0 + n];
        p.h[1] = (bf16_t)xb[(size_t)(c + 1) * Nn + n0 + n];
        unsigned byte = n * 256 + ((unsigned)(c * 2) ^ ((n & 7) << 4));
        *(unsigned*)(smem + byte) = p.u;
    }
    const float* wpg = Wp + (size_t)h * 96 * Cc;
    #pragma unroll
    for (int it = 0; it < 24; ++it) {
        int idx = t + it * 256;
        int row = idx >> 6;
        int col = (idx & 63) * 2;
        BPack p;
        p.h[0] = (bf16_t)wpg[row * Cc + col];
        p.h[1] = (bf16_t)wpg[row * Cc + col + 1];
        unsigned byte = 16384 + row * 256 + ((unsigned)(col * 2) ^ ((row & 7) << 4));
        *(unsigned*)(smem + byte) = p.u;
    }
    __syncthreads();

    f32x4 acc[6] = {};
    #pragma unroll
    for (int kc = 0; kc < 4; ++kc) {
        int cb = (kc * 32 + g * 8) * 2;
        int rowA = w * 16 + a;
        bf16x8 af = *(const bf16x8*)(smem + rowA * 256 + (cb ^ ((rowA & 7) << 4)));
        #pragma unroll
        for (int pt = 0; pt < 6; ++pt) {
            int rowB = pt * 16 + a;
            bf16x8 bfr = *(const bf16x8*)(smem + 16384 + rowB * 256 + (cb ^ ((rowB & 7) << 4)));
            acc[pt] = MFMA16(af, bfr, acc[pt]);
        }
    }

    const int bh = b * NH + h;
    #pragma unroll
    for (int pt = 0; pt < 4; ++pt) {
        const int which = pt >> 1;
        const int d = (pt & 1) * 16 + a;
        const float bias = bp[h * 96 + which * 32 + d];
        bf16_t* dst = which ? k_s : q_s;
        const float sc = which ? 1.0f : QSCALE;
        #pragma unroll
        for (int r = 0; r < 4; ++r) {
            int n = n0 + w * 16 + g * 4 + r;
            dst[((size_t)bh * Nn + n) * DK + d] = (bf16_t)((acc[pt][r] + bias) * sc);
        }
    }
    __syncthreads();
    bf16_t* vt_l = (bf16_t*)smem;
    #pragma unroll
    for (int pt = 4; pt < 6; ++pt) {
        const int d = (pt & 1) * 16 + a;
        const float bias = bp[h * 96 + 64 + d];
        #pragma unroll
        for (int r = 0; r < 4; ++r) {
            int nl = w * 16 + g * 4 + r;
            vt_l[d * 72 + nl] = (bf16_t)(acc[pt][r] + bias);
        }
    }
    __syncthreads();
    #pragma unroll
    for (int it = 0; it < 8; ++it) {
        int idx = t + it * 256;
        int d = idx >> 6, n = idx & 63;
        int m = n & 31;
        int col = ((m & 15) << 1) | (m >> 4);
        int jj = (n & 32) | col;
        vt_s[((size_t)bh * DK + d) * Nn + n0 + jj] = vt_l[d * 72 + n];
    }
}

// ---------------------------------------------------------------------------
// K2: partial column sums. S_part[is][bh][j] = sum_{i in split is} 2^t[i,j].
// R11-proven widened structure: wave owns 32 j (2 K-fragments), 32 i/iter
// (2 qf loads, 4 MFMA, 16 exp2, 4 acc sets). No manual prefetch, no
// min-waves clause (R6/R7 spill lessons). Grid: 2048 blocks.
// ---------------------------------------------------------------------------
__global__ __launch_bounds__(256) void k_stats(const bf16_t* __restrict__ q_s,
                                               const bf16_t* __restrict__ k_s,
                                               float* __restrict__ S_part)
{
    const int bx = blockIdx.x;
    const int is = bx & 3;
    const int jc = (bx >> 2) & 31;
    const int bh = bx >> 7;
    const int t = threadIdx.x, w = t >> 6, lane = t & 63, a = lane & 15, g = lane >> 4;
    const bf16_t* Q = q_s + (size_t)bh * Nn * DK;
    const bf16_t* K = k_s + (size_t)bh * Nn * DK;
    const int jb = jc * 128 + w * 32;
    bf16x8 kf0 = *(const bf16x8*)(K + (jb + a) * DK + g * 8);
    bf16x8 kf1 = *(const bf16x8*)(K + (jb + 16 + a) * DK + g * 8);
    f32x4 l0 = {}, l1 = {}, l2 = {}, l3 = {};
    const int ilo = is * (Nn / 4);
    #pragma unroll 2
    for (int i0 = ilo; i0 < ilo + Nn / 4; i0 += 32) {
        bf16x8 qfA = *(const bf16x8*)(Q + (i0 + a) * DK + g * 8);
        bf16x8 qfB = *(const bf16x8*)(Q + (i0 + 16 + a) * DK + g * 8);
        f32x4 z = {};
        f32x4 t0 = MFMA16(qfA, kf0, z);
        f32x4 t1 = MFMA16(qfA, kf1, z);
        f32x4 t2 = MFMA16(qfB, kf0, z);
        f32x4 t3 = MFMA16(qfB, kf1, z);
        #pragma unroll
        for (int r = 0; r < 4; ++r) {
            l0[r] += exp2_f(t0[r]);
            l1[r] += exp2_f(t1[r]);
            l2[r] += exp2_f(t2[r]);
            l3[r] += exp2_f(t3[r]);
        }
    }
    l0 += l2;
    l1 += l3;
    float s0 = l0[0] + l0[1] + l0[2] + l0[3];
    float s1 = l1[0] + l1[1] + l1[2] + l1[3];
    s0 += __shfl_xor(s0, 16);
    s0 += __shfl_xor(s0, 32);
    s1 += __shfl_xor(s1, 16);
    s1 += __shfl_xor(s1, 32);
    if (g == 0) {
        float* Sp = S_part + ((size_t)is * 16 + bh) * Nn;
        Sp[jb + a]      = s0;
        Sp[jb + 16 + a] = s1;
    }
}

// ---------------------------------------------------------------------------
// K2b: S_j = sum of 4 partials; scale vt_s rows in place by 1/S[p(J)].
// ---------------------------------------------------------------------------
__global__ __launch_bounds__(256) void k_vscale(const float* __restrict__ S_part,
                                                bf16_t* __restrict__ vt_s)
{
    __shared__ float sinv[512];
    const int Jb = blockIdx.x;   // 0..7, 512 J each
    const int bh = blockIdx.y;   // 0..15
    const int t = threadIdx.x;
    if (t < 128) {
        #pragma unroll
        for (int k2 = 0; k2 < 4; ++k2) {
            int Jl = t * 4 + k2;
            int m = Jl & 31;
            int pJ = (Jl & ~31) | (m >> 1) | ((m & 1) << 4);  // inverse of k_qkv's store permutation
            int J = Jb * 512 + pJ;
            float s = 0.f;
            #pragma unroll
            for (int is = 0; is < 4; ++is)
                s += S_part[((size_t)is * 16 + bh) * Nn + J];
            sinv[Jl] = 1.0f / s;
        }
    }
    __syncthreads();
    bf16_t* vrow = vt_s + (size_t)bh * DK * Nn;
    #pragma unroll
    for (int it = 0; it < 8; ++it) {
        int idx = t + it * 256;
        int d = idx >> 6, Jg = (idx & 63) * 8;
        bf16_t* p = vrow + (size_t)d * Nn + Jb * 512 + Jg;
        bf16x8 v = *(const bf16x8*)p;
        #pragma unroll
        for (int k2 = 0; k2 < 8; ++k2) v[k2] = (bf16_t)((float)v[k2] * sinv[Jg + k2]);
        *(bf16x8*)p = v;
    }
}

// ---------------------------------------------------------------------------
// K3: O[i,d] = sum_j 2^t[i,j] * V'[j,d], j-split into bf16 pair-packed
// partials. R8-proven body: swapped QK^T keeps P in registers; wave holds
// 64 i (4 Q-fragments); 4 kf/vf loads per 32-j chunk feed 16 MFMA + 32 exp2
// with explicit 1-chunk prefetch. T5: setprio(1) around the compute cluster
// (barrier-free independent waves = the m191 attn regime where it measured
// +4-7%; null only on lockstep GEMM).
// ---------------------------------------------------------------------------
template<int JSPAN>
__global__ __launch_bounds__(256, 4) void k_attn(const bf16_t* __restrict__ q_s,
                                                 const bf16_t* __restrict__ k_s,
                                                 const bf16_t* __restrict__ vt_s,
                                                 unsigned* __restrict__ opart)
{
    constexpr int NJS = Nn / JSPAN;
    const int bx = blockIdx.x;
    const int js = bx % NJS;
    const int ic = (bx / NJS) & 15;
    const int bh = bx / (NJS * 16);
    const int b = bh >> 2, h = bh & 3;
    const int t = threadIdx.x, w = t >> 6, lane = t & 63, a = lane & 15, g = lane >> 4;
    const int ib = ic * 256 + w * 64;
    const bf16_t* Q  = q_s  + (size_t)bh * Nn * DK;
    const bf16_t* K  = k_s  + (size_t)bh * Nn * DK;
    const bf16_t* Vt = vt_s + (size_t)bh * DK * Nn;
    bf16x8 qf[4];
    #pragma unroll
    for (int it = 0; it < 4; ++it)
        qf[it] = *(const bf16x8*)(Q + (size_t)(ib + it * 16 + a) * DK + g * 8);
    f32x4 o0[4] = {}, o1[4] = {};
    auto compute = [&](bf16x8 ck0, bf16x8 ck1, bf16x8 cv0, bf16x8 cv1) {
        f32x4 z = {};
        __builtin_amdgcn_s_setprio(1);
        #pragma unroll
        for (int it = 0; it < 4; ++it) {
            f32x4 s0 = MFMA16(ck0, qf[it], z);   // S^T: rows=j-tile0, cols=i
            f32x4 s1 = MFMA16(ck1, qf[it], z);   // S^T: rows=j-tile1, cols=i
            bf16x8 pa;
            #pragma unroll
            for (int r = 0; r < 4; ++r) {
                pa[2 * r]     = (bf16_t)exp2_f(s0[r]);
                pa[2 * r + 1] = (bf16_t)exp2_f(s1[r]);
            }
            o0[it] = MFMA16(pa, cv0, o0[it]);
            o1[it] = MFMA16(pa, cv1, o1[it]);
        }
        __builtin_amdgcn_s_setprio(0);
    };
    const int jlo = js * JSPAN;
    bf16x8 kf0 = *(const bf16x8*)(K + (size_t)(jlo + a) * DK + g * 8);
    bf16x8 kf1 = *(const bf16x8*)(K + (size_t)(jlo + 16 + a) * DK + g * 8);
    bf16x8 vf0 = *(const bf16x8*)(Vt + (size_t)a * Nn + jlo + g * 8);
    bf16x8 vf1 = *(const bf16x8*)(Vt + (size_t)(16 + a) * Nn + jlo + g * 8);
    #pragma unroll 2
    for (int j0 = jlo; j0 < jlo + JSPAN - 32; j0 += 32) {
        bf16x8 ck0 = kf0, ck1 = kf1, cv0 = vf0, cv1 = vf1;
        kf0 = *(const bf16x8*)(K + (size_t)(j0 + 32 + a) * DK + g * 8);
        kf1 = *(const bf16x8*)(K + (size_t)(j0 + 48 + a) * DK + g * 8);
        vf0 = *(const bf16x8*)(Vt + (size_t)a * Nn + j0 + 32 + g * 8);
        vf1 = *(const bf16x8*)(Vt + (size_t)(16 + a) * Nn + j0 + 32 + g * 8);
        compute(ck0, ck1, cv0, cv1);
    }
    compute(kf0, kf1, vf0, vf1);

    // pair-packed store: word (h*16 + a) of row n holds channels (h*32+a, h*32+16+a)
    unsigned* Ob = opart + ((size_t)(js * Bn + b) * Nn) * 64 + h * 16 + a;
    #pragma unroll
    for (int it = 0; it < 4; ++it) {
        #pragma unroll
        for (int r = 0; r < 4; ++r) {
            int n = ib + it * 16 + g * 4 + r;
            BPack p;
            p.h[0] = (bf16_t)o0[it][r];
            p.h[1] = (bf16_t)o1[it][r];
            Ob[(size_t)n * 64] = p.u;
        }
    }
}

// ---------------------------------------------------------------------------
// K4: out[b][c][n] = ((sum_js opart) @ Wo^T)[n][c] + bo[c] + x[b][c][n]
// opart is u32 pair-packed bf16. NJS is now a TEMPLATE constant so the
// js-reduction fully unrolls (R10 lesson: runtime trip counts serialize
// loads; k_out runs at only 1 block/CU so exposed latency is unforgiving).
// ---------------------------------------------------------------------------
template<int NJS>
__global__ __launch_bounds__(256) void k_out(const unsigned* __restrict__ opart,
                                             const float* __restrict__ Wo,
                                             const float* __restrict__ bo,
                                             const float* __restrict__ x,
                                             float* __restrict__ out)
{
    __shared__ __attribute__((aligned(16))) char smem[33280]; // Wo bf16 32KB, then out_t [128][65] f32
    const int n0 = blockIdx.x * 64;
    const int b = blockIdx.y;
    const int t = threadIdx.x, w = t >> 6, lane = t & 63, a = lane & 15, g = lane >> 4;
    #pragma unroll
    for (int it = 0; it < 32; ++it) {
        int idx = t + it * 256;
        int row = idx >> 6;
        int col = (idx & 63) * 2;
        BPack p;
        p.h[0] = (bf16_t)Wo[row * 128 + col];
        p.h[1] = (bf16_t)Wo[row * 128 + col + 1];
        unsigned byte = row * 256 + ((unsigned)(col * 2) ^ ((row & 7) << 4));
        *(unsigned*)(smem + byte) = p.u;
    }
    __syncthreads();
    const size_t OSTR32 = (size_t)Bn * Nn * 64;
    const unsigned* Ob = opart + ((size_t)b * Nn + n0 + w * 16 + a) * 64;
    const unsigned hi = (g >= 2);
    const int wsub = (g & 1) * 8;
    f32x4 acc[8] = {};
    #pragma unroll
    for (int kc = 0; kc < 4; ++kc) {
        float s[8] = {};
        #pragma unroll
        for (int js = 0; js < NJS; ++js) {
            const unsigned* pp = Ob + (size_t)js * OSTR32 + kc * 16 + wsub;
            u32x4 v0 = *(const u32x4*)pp;
            u32x4 v1 = *(const u32x4*)(pp + 4);
            #pragma unroll
            for (int k2 = 0; k2 < 4; ++k2) {
                s[k2]     += __uint_as_float(hi ? (v0[k2] & 0xffff0000u) : (v0[k2] << 16));
                s[k2 + 4] += __uint_as_float(hi ? (v1[k2] & 0xffff0000u) : (v1[k2] << 16));
            }
        }
        bf16x8 af;
        #pragma unroll
        for (int k2 = 0; k2 < 8; ++k2) af[k2] = (bf16_t)s[k2];
        int cb = (kc * 32 + g * 8) * 2;
        #pragma unroll
        for (int ct = 0; ct < 8; ++ct) {
            int rowB = ct * 16 + a;
            bf16x8 bfr = *(const bf16x8*)(smem + rowB * 256 + (cb ^ ((rowB & 7) << 4)));
            acc[ct] = MFMA16(af, bfr, acc[ct]);
        }
    }
    __syncthreads();
    float* out_t = (float*)smem;   // [128][65]
    #pragma unroll
    for (int ct = 0; ct < 8; ++ct) {
        int c = ct * 16 + a;
        #pragma unroll
        for (int r = 0; r < 4; ++r) {
            out_t[c * 65 + w * 16 + g * 4 + r] = acc[ct][r];
        }
    }
    __syncthreads();
    const float* xb = x + (size_t)b * Cc * Nn;
    #pragma unroll
    for (int it = 0; it < 32; ++it) {
        int idx = t + it * 256;
        int c = idx >> 6, n = idx & 63;
        out[((size_t)b * Cc + c) * Nn + n0 + n] = out_t[c * 65 + n] + xb[(size_t)c * Nn + n0 + n] + bo[c];
    }
}

extern "C" void kernel_launch(void* const* d_in, const int* in_sizes, int n_in,
                              void* d_out, int out_size, void* d_ws, size_t ws_size,
                              hipStream_t stream)
{
    const float* x  = (const float*)d_in[0];
    const float* Wp = (const float*)d_in[1];
    const float* bp = (const float*)d_in[2];
    const float* Wo = (const float*)d_in[3];
    const float* bo = (const float*)d_in[4];
    float* out = (float*)d_out;

    char* ws = (char*)d_ws;
    bf16_t*  q_s   = (bf16_t*)(ws);                 // 4 MB
    bf16_t*  k_s   = (bf16_t*)(ws + (4  << 20));    // 4 MB
    bf16_t*  vt_s  = (bf16_t*)(ws + (8  << 20));    // 4 MB
    float*   S_part= (float*) (ws + (12 << 20));    // 1 MB (4 splits x 16bh x 4096 f32)
    unsigned* opart= (unsigned*)(ws + (13 << 20));  // NJS x 4 MB (bf16 pair-packed)

    const size_t base = 13ull << 20;
    const size_t plane = 4ull << 20;
    int NJS = 1;
    if (ws_size >= base + 4 * plane) NJS = 4;
    else if (ws_size >= base + 2 * plane) NJS = 2;

    k_qkv   <<<dim3(Nn / 64, Bn, NH),   256, 0, stream>>>(x, Wp, bp, q_s, k_s, vt_s);
    k_stats <<<16 * 32 * 4,             256, 0, stream>>>(q_s, k_s, S_part);
    k_vscale<<<dim3(8, 16),             256, 0, stream>>>(S_part, vt_s);
    if (NJS == 4) {
        k_attn<1024><<<16 * 16 * 4, 256, 0, stream>>>(q_s, k_s, vt_s, opart);
        k_out<4><<<dim3(Nn / 64, Bn), 256, 0, stream>>>(opart, Wo, bo, x, out);
    } else if (NJS == 2) {
        k_attn<2048><<<16 * 16 * 2, 256, 0, stream>>>(q_s, k_s, vt_s, opart);
        k_out<2><<<dim3(Nn / 64, Bn), 256, 0, stream>>>(opart, Wo, bo, x, out);
    } else {
        k_attn<4096><<<16 * 16 * 1, 256, 0, stream>>>(q_s, k_s, vt_s, opart);
        k_out<1><<<dim3(Nn / 64, Bn), 256, 0, stream>>>(opart, Wo, bo, x, out);
    }
}

// Round 13
// 190.750 us; speedup vs baseline: 1.0017x; 1.0017x over previous
//
#include <hip/hip_runtime.h>

typedef __bf16 bf16_t;
typedef __bf16 bf16x8 __attribute__((ext_vector_type(8)));
typedef float  f32x4  __attribute__((ext_vector_type(4)));
typedef unsigned u32x4 __attribute__((ext_vector_type(4)));

#define MFMA16(a, b, c) __builtin_amdgcn_mfma_f32_16x16x32_bf16((a), (b), (c), 0, 0, 0)

__device__ __forceinline__ float exp2_f(float x) { return __builtin_amdgcn_exp2f(x); }

union BPack { bf16_t h[2]; unsigned u; };

constexpr int Bn = 4, Cc = 128, Nn = 4096, NH = 4, DK = 32;
// fold 1/sqrt(32) * log2(e) into stored Q so MFMA emits exp2-domain logits
constexpr float QSCALE = 0.176776695f * 1.44269504f;

// ---------------------------------------------------------------------------
// K1: fused transpose + QKV projection.
//   v -> vt_s[bh][d][J] transposed; stored value at J is V[p(J)],
//   p(J)=(J&~31)+((J&31)>>1)+((J&1)*16)  (matches MFMA A/B k-slot interleave)
// ---------------------------------------------------------------------------
__global__ __launch_bounds__(256) void k_qkv(const float* __restrict__ x,
                                             const float* __restrict__ Wp,
                                             const float* __restrict__ bp,
                                             bf16_t* __restrict__ q_s,
                                             bf16_t* __restrict__ k_s,
                                             bf16_t* __restrict__ vt_s)
{
    __shared__ __attribute__((aligned(16))) char smem[40960]; // xs 16KB + wp 24KB
    const int n0 = blockIdx.x * 64;
    const int b  = blockIdx.y;
    const int h  = blockIdx.z;
    const int t  = threadIdx.x;
    const int w = t >> 6, lane = t & 63, a = lane & 15, g = lane >> 4;

    const float* xb = x + (size_t)b * Cc * Nn;
    #pragma unroll
    for (int it = 0; it < 16; ++it) {
        int c = ((t >> 6) + it * 4) * 2;
        int n = t & 63;
        BPack p;
        p.h[0] = (bf16_t)xb[(size_t)c * Nn + n0 + n];
        p.h[1] = (bf16_t)xb[(size_t)(c + 1) * Nn + n0 + n];
        unsigned byte = n * 256 + ((unsigned)(c * 2) ^ ((n & 7) << 4));
        *(unsigned*)(smem + byte) = p.u;
    }
    const float* wpg = Wp + (size_t)h * 96 * Cc;
    #pragma unroll
    for (int it = 0; it < 24; ++it) {
        int idx = t + it * 256;
        int row = idx >> 6;
        int col = (idx & 63) * 2;
        BPack p;
        p.h[0] = (bf16_t)wpg[row * Cc + col];
        p.h[1] = (bf16_t)wpg[row * Cc + col + 1];
        unsigned byte = 16384 + row * 256 + ((unsigned)(col * 2) ^ ((row & 7) << 4));
        *(unsigned*)(smem + byte) = p.u;
    }
    __syncthreads();

    f32x4 acc[6] = {};
    #pragma unroll
    for (int kc = 0; kc < 4; ++kc) {
        int cb = (kc * 32 + g * 8) * 2;
        int rowA = w * 16 + a;
        bf16x8 af = *(const bf16x8*)(smem + rowA * 256 + (cb ^ ((rowA & 7) << 4)));
        #pragma unroll
        for (int pt = 0; pt < 6; ++pt) {
            int rowB = pt * 16 + a;
            bf16x8 bfr = *(const bf16x8*)(smem + 16384 + rowB * 256 + (cb ^ ((rowB & 7) << 4)));
            acc[pt] = MFMA16(af, bfr, acc[pt]);
        }
    }

    const int bh = b * NH + h;
    #pragma unroll
    for (int pt = 0; pt < 4; ++pt) {
        const int which = pt >> 1;
        const int d = (pt & 1) * 16 + a;
        const float bias = bp[h * 96 + which * 32 + d];
        bf16_t* dst = which ? k_s : q_s;
        const float sc = which ? 1.0f : QSCALE;
        #pragma unroll
        for (int r = 0; r < 4; ++r) {
            int n = n0 + w * 16 + g * 4 + r;
            dst[((size_t)bh * Nn + n) * DK + d] = (bf16_t)((acc[pt][r] + bias) * sc);
        }
    }
    __syncthreads();
    bf16_t* vt_l = (bf16_t*)smem;
    #pragma unroll
    for (int pt = 4; pt < 6; ++pt) {
        const int d = (pt & 1) * 16 + a;
        const float bias = bp[h * 96 + 64 + d];
        #pragma unroll
        for (int r = 0; r < 4; ++r) {
            int nl = w * 16 + g * 4 + r;
            vt_l[d * 72 + nl] = (bf16_t)(acc[pt][r] + bias);
        }
    }
    __syncthreads();
    #pragma unroll
    for (int it = 0; it < 8; ++it) {
        int idx = t + it * 256;
        int d = idx >> 6, n = idx & 63;
        int m = n & 31;
        int col = ((m & 15) << 1) | (m >> 4);
        int jj = (n & 32) | col;
        vt_s[((size_t)bh * DK + d) * Nn + n0 + jj] = vt_l[d * 72 + n];
    }
}

// ---------------------------------------------------------------------------
// K2: partial column sums. S_part[is][bh][j] = sum_{i in split is} 2^t[i,j].
// R11-proven widened structure + T1 XCD swizzle: consecutive wgids share bh
// (K/Q 512 KB/bh); packing each bh's blocks onto one XCD makes them
// L2-resident instead of bouncing through L3. Grid 2048 (2048%8==0,
// bijective chunk swizzle). No manual prefetch, no min-waves (R6/R7).
// ---------------------------------------------------------------------------
__global__ __launch_bounds__(256) void k_stats(const bf16_t* __restrict__ q_s,
                                               const bf16_t* __restrict__ k_s,
                                               float* __restrict__ S_part)
{
    const int bid = blockIdx.x;
    const int bx = (bid & 7) * 256 + (bid >> 3);   // XCD-chunk swizzle, 2048 blocks
    const int is = bx & 3;
    const int jc = (bx >> 2) & 31;
    const int bh = bx >> 7;
    const int t = threadIdx.x, w = t >> 6, lane = t & 63, a = lane & 15, g = lane >> 4;
    const bf16_t* Q = q_s + (size_t)bh * Nn * DK;
    const bf16_t* K = k_s + (size_t)bh * Nn * DK;
    const int jb = jc * 128 + w * 32;
    bf16x8 kf0 = *(const bf16x8*)(K + (jb + a) * DK + g * 8);
    bf16x8 kf1 = *(const bf16x8*)(K + (jb + 16 + a) * DK + g * 8);
    f32x4 l0 = {}, l1 = {}, l2 = {}, l3 = {};
    const int ilo = is * (Nn / 4);
    #pragma unroll 2
    for (int i0 = ilo; i0 < ilo + Nn / 4; i0 += 32) {
        bf16x8 qfA = *(const bf16x8*)(Q + (i0 + a) * DK + g * 8);
        bf16x8 qfB = *(const bf16x8*)(Q + (i0 + 16 + a) * DK + g * 8);
        f32x4 z = {};
        f32x4 t0 = MFMA16(qfA, kf0, z);
        f32x4 t1 = MFMA16(qfA, kf1, z);
        f32x4 t2 = MFMA16(qfB, kf0, z);
        f32x4 t3 = MFMA16(qfB, kf1, z);
        #pragma unroll
        for (int r = 0; r < 4; ++r) {
            l0[r] += exp2_f(t0[r]);
            l1[r] += exp2_f(t1[r]);
            l2[r] += exp2_f(t2[r]);
            l3[r] += exp2_f(t3[r]);
        }
    }
    l0 += l2;
    l1 += l3;
    float s0 = l0[0] + l0[1] + l0[2] + l0[3];
    float s1 = l1[0] + l1[1] + l1[2] + l1[3];
    s0 += __shfl_xor(s0, 16);
    s0 += __shfl_xor(s0, 32);
    s1 += __shfl_xor(s1, 16);
    s1 += __shfl_xor(s1, 32);
    if (g == 0) {
        float* Sp = S_part + ((size_t)is * 16 + bh) * Nn;
        Sp[jb + a]      = s0;
        Sp[jb + 16 + a] = s1;
    }
}

// ---------------------------------------------------------------------------
// K2b: S_j = sum of 4 partials; scale vt_s rows in place by 1/S[p(J)].
// ---------------------------------------------------------------------------
__global__ __launch_bounds__(256) void k_vscale(const float* __restrict__ S_part,
                                                bf16_t* __restrict__ vt_s)
{
    __shared__ float sinv[512];
    const int Jb = blockIdx.x;   // 0..7, 512 J each
    const int bh = blockIdx.y;   // 0..15
    const int t = threadIdx.x;
    if (t < 128) {
        #pragma unroll
        for (int k2 = 0; k2 < 4; ++k2) {
            int Jl = t * 4 + k2;
            int m = Jl & 31;
            int pJ = (Jl & ~31) | (m >> 1) | ((m & 1) << 4);  // inverse of k_qkv's store permutation
            int J = Jb * 512 + pJ;
            float s = 0.f;
            #pragma unroll
            for (int is = 0; is < 4; ++is)
                s += S_part[((size_t)is * 16 + bh) * Nn + J];
            sinv[Jl] = 1.0f / s;
        }
    }
    __syncthreads();
    bf16_t* vrow = vt_s + (size_t)bh * DK * Nn;
    #pragma unroll
    for (int it = 0; it < 8; ++it) {
        int idx = t + it * 256;
        int d = idx >> 6, Jg = (idx & 63) * 8;
        bf16_t* p = vrow + (size_t)d * Nn + Jb * 512 + Jg;
        bf16x8 v = *(const bf16x8*)p;
        #pragma unroll
        for (int k2 = 0; k2 < 8; ++k2) v[k2] = (bf16_t)((float)v[k2] * sinv[Jg + k2]);
        *(bf16x8*)p = v;
    }
}

// ---------------------------------------------------------------------------
// K3: O[i,d] = sum_j 2^t[i,j] * V'[j,d], j-split into bf16 pair-packed
// partials. R8-proven 64-i body (setprio reverted: R12 A/B showed null at
// +4 VGPR). New: (a) T1 XCD swizzle — pack each bh's blocks onto one XCD so
// K/V stay L2-resident; (b) DEPTH-2 prefetch via two NAMED buffer sets
// (no runtime-indexed arrays -> no scratch), load->use distance ~2 compute
// blocks (~700 cyc). #pragma unroll 1 pins the loop so the compiler doesn't
// stack its own pipelining on top (R6/R7 spill lessons).
// ---------------------------------------------------------------------------
template<int JSPAN>
__global__ __launch_bounds__(256, 4) void k_attn(const bf16_t* __restrict__ q_s,
                                                 const bf16_t* __restrict__ k_s,
                                                 const bf16_t* __restrict__ vt_s,
                                                 unsigned* __restrict__ opart)
{
    constexpr int NJS = Nn / JSPAN;
    constexpr int NWG = 16 * 16 * NJS;
    const int bid = blockIdx.x;
    const int bx = (bid & 7) * (NWG / 8) + (bid >> 3);   // XCD-chunk swizzle
    const int js = bx % NJS;
    const int ic = (bx / NJS) & 15;
    const int bh = bx / (NJS * 16);
    const int b = bh >> 2, h = bh & 3;
    const int t = threadIdx.x, w = t >> 6, lane = t & 63, a = lane & 15, g = lane >> 4;
    const int ib = ic * 256 + w * 64;
    const bf16_t* Q  = q_s  + (size_t)bh * Nn * DK;
    const bf16_t* K  = k_s  + (size_t)bh * Nn * DK;
    const bf16_t* Vt = vt_s + (size_t)bh * DK * Nn;
    bf16x8 qf[4];
    #pragma unroll
    for (int it = 0; it < 4; ++it)
        qf[it] = *(const bf16x8*)(Q + (size_t)(ib + it * 16 + a) * DK + g * 8);
    f32x4 o0[4] = {}, o1[4] = {};
    auto compute = [&](bf16x8 ck0, bf16x8 ck1, bf16x8 cv0, bf16x8 cv1) {
        f32x4 z = {};
        #pragma unroll
        for (int it = 0; it < 4; ++it) {
            f32x4 s0 = MFMA16(ck0, qf[it], z);   // S^T: rows=j-tile0, cols=i
            f32x4 s1 = MFMA16(ck1, qf[it], z);   // S^T: rows=j-tile1, cols=i
            bf16x8 pa;
            #pragma unroll
            for (int r = 0; r < 4; ++r) {
                pa[2 * r]     = (bf16_t)exp2_f(s0[r]);
                pa[2 * r + 1] = (bf16_t)exp2_f(s1[r]);
            }
            o0[it] = MFMA16(pa, cv0, o0[it]);
            o1[it] = MFMA16(pa, cv1, o1[it]);
        }
    };
    const int jlo = js * JSPAN;
    #define LOADJ(K0, K1, V0, V1, J) \
        K0 = *(const bf16x8*)(K + (size_t)((J) + a) * DK + g * 8); \
        K1 = *(const bf16x8*)(K + (size_t)((J) + 16 + a) * DK + g * 8); \
        V0 = *(const bf16x8*)(Vt + (size_t)a * Nn + (J) + g * 8); \
        V1 = *(const bf16x8*)(Vt + (size_t)(16 + a) * Nn + (J) + g * 8)

    bf16x8 kA0, kA1, vA0, vA1, kB0, kB1, vB0, vB1;
    LOADJ(kA0, kA1, vA0, vA1, jlo);
    LOADJ(kB0, kB1, vB0, vB1, jlo + 32);
    #pragma unroll 1
    for (int j0 = jlo; j0 < jlo + JSPAN - 64; j0 += 64) {
        bf16x8 t0 = kA0, t1 = kA1, t2 = vA0, t3 = vA1;
        LOADJ(kA0, kA1, vA0, vA1, j0 + 64);
        compute(t0, t1, t2, t3);
        bf16x8 u0 = kB0, u1 = kB1, u2 = vB0, u3 = vB1;
        LOADJ(kB0, kB1, vB0, vB1, j0 + 96);
        compute(u0, u1, u2, u3);
    }
    compute(kA0, kA1, vA0, vA1);
    compute(kB0, kB1, vB0, vB1);
    #undef LOADJ

    // pair-packed store: word (h*16 + a) of row n holds channels (h*32+a, h*32+16+a)
    unsigned* Ob = opart + ((size_t)(js * Bn + b) * Nn) * 64 + h * 16 + a;
    #pragma unroll
    for (int it = 0; it < 4; ++it) {
        #pragma unroll
        for (int r = 0; r < 4; ++r) {
            int n = ib + it * 16 + g * 4 + r;
            BPack p;
            p.h[0] = (bf16_t)o0[it][r];
            p.h[1] = (bf16_t)o1[it][r];
            Ob[(size_t)n * 64] = p.u;
        }
    }
}

// ---------------------------------------------------------------------------
// K4: out[b][c][n] = ((sum_js opart) @ Wo^T)[n][c] + bo[c] + x[b][c][n]
// opart is u32 pair-packed bf16. NJS templated -> js-reduction fully unrolls.
// ---------------------------------------------------------------------------
template<int NJS>
__global__ __launch_bounds__(256) void k_out(const unsigned* __restrict__ opart,
                                             const float* __restrict__ Wo,
                                             const float* __restrict__ bo,
                                             const float* __restrict__ x,
                                             float* __restrict__ out)
{
    __shared__ __attribute__((aligned(16))) char smem[33280]; // Wo bf16 32KB, then out_t [128][65] f32
    const int n0 = blockIdx.x * 64;
    const int b = blockIdx.y;
    const int t = threadIdx.x, w = t >> 6, lane = t & 63, a = lane & 15, g = lane >> 4;
    #pragma unroll
    for (int it = 0; it < 32; ++it) {
        int idx = t + it * 256;
        int row = idx >> 6;
        int col = (idx & 63) * 2;
        BPack p;
        p.h[0] = (bf16_t)Wo[row * 128 + col];
        p.h[1] = (bf16_t)Wo[row * 128 + col + 1];
        unsigned byte = row * 256 + ((unsigned)(col * 2) ^ ((row & 7) << 4));
        *(unsigned*)(smem + byte) = p.u;
    }
    __syncthreads();
    const size_t OSTR32 = (size_t)Bn * Nn * 64;
    const unsigned* Ob = opart + ((size_t)b * Nn + n0 + w * 16 + a) * 64;
    const unsigned hi = (g >= 2);
    const int wsub = (g & 1) * 8;
    f32x4 acc[8] = {};
    #pragma unroll
    for (int kc = 0; kc < 4; ++kc) {
        float s[8] = {};
        #pragma unroll
        for (int js = 0; js < NJS; ++js) {
            const unsigned* pp = Ob + (size_t)js * OSTR32 + kc * 16 + wsub;
            u32x4 v0 = *(const u32x4*)pp;
            u32x4 v1 = *(const u32x4*)(pp + 4);
            #pragma unroll
            for (int k2 = 0; k2 < 4; ++k2) {
                s[k2]     += __uint_as_float(hi ? (v0[k2] & 0xffff0000u) : (v0[k2] << 16));
                s[k2 + 4] += __uint_as_float(hi ? (v1[k2] & 0xffff0000u) : (v1[k2] << 16));
            }
        }
        bf16x8 af;
        #pragma unroll
        for (int k2 = 0; k2 < 8; ++k2) af[k2] = (bf16_t)s[k2];
        int cb = (kc * 32 + g * 8) * 2;
        #pragma unroll
        for (int ct = 0; ct < 8; ++ct) {
            int rowB = ct * 16 + a;
            bf16x8 bfr = *(const bf16x8*)(smem + rowB * 256 + (cb ^ ((rowB & 7) << 4)));
            acc[ct] = MFMA16(af, bfr, acc[ct]);
        }
    }
    __syncthreads();
    float* out_t = (float*)smem;   // [128][65]
    #pragma unroll
    for (int ct = 0; ct < 8; ++ct) {
        int c = ct * 16 + a;
        #pragma unroll
        for (int r = 0; r < 4; ++r) {
            out_t[c * 65 + w * 16 + g * 4 + r] = acc[ct][r];
        }
    }
    __syncthreads();
    const float* xb = x + (size_t)b * Cc * Nn;
    #pragma unroll
    for (int it = 0; it < 32; ++it) {
        int idx = t + it * 256;
        int c = idx >> 6, n = idx & 63;
        out[((size_t)b * Cc + c) * Nn + n0 + n] = out_t[c * 65 + n] + xb[(size_t)c * Nn + n0 + n] + bo[c];
    }
}

extern "C" void kernel_launch(void* const* d_in, const int* in_sizes, int n_in,
                              void* d_out, int out_size, void* d_ws, size_t ws_size,
                              hipStream_t stream)
{
    const float* x  = (const float*)d_in[0];
    const float* Wp = (const float*)d_in[1];
    const float* bp = (const float*)d_in[2];
    const float* Wo = (const float*)d_in[3];
    const float* bo = (const float*)d_in[4];
    float* out = (float*)d_out;

    char* ws = (char*)d_ws;
    bf16_t*  q_s   = (bf16_t*)(ws);                 // 4 MB
    bf16_t*  k_s   = (bf16_t*)(ws + (4  << 20));    // 4 MB
    bf16_t*  vt_s  = (bf16_t*)(ws + (8  << 20));    // 4 MB
    float*   S_part= (float*) (ws + (12 << 20));    // 1 MB (4 splits x 16bh x 4096 f32)
    unsigned* opart= (unsigned*)(ws + (13 << 20));  // NJS x 4 MB (bf16 pair-packed)

    const size_t base = 13ull << 20;
    const size_t plane = 4ull << 20;
    int NJS = 1;
    if (ws_size >= base + 4 * plane) NJS = 4;
    else if (ws_size >= base + 2 * plane) NJS = 2;

    k_qkv   <<<dim3(Nn / 64, Bn, NH),   256, 0, stream>>>(x, Wp, bp, q_s, k_s, vt_s);
    k_stats <<<16 * 32 * 4,             256, 0, stream>>>(q_s, k_s, S_part);
    k_vscale<<<dim3(8, 16),             256, 0, stream>>>(S_part, vt_s);
    if (NJS == 4) {
        k_attn<1024><<<16 * 16 * 4, 256, 0, stream>>>(q_s, k_s, vt_s, opart);
        k_out<4><<<dim3(Nn / 64, Bn), 256, 0, stream>>>(opart, Wo, bo, x, out);
    } else if (NJS == 2) {
        k_attn<2048><<<16 * 16 * 2, 256, 0, stream>>>(q_s, k_s, vt_s, opart);
        k_out<2><<<dim3(Nn / 64, Bn), 256, 0, stream>>>(opart, Wo, bo, x, out);
    } else {
        k_attn<4096><<<16 * 16 * 1, 256, 0, stream>>>(q_s, k_s, vt_s, opart);
        k_out<1><<<dim3(Nn / 64, Bn), 256, 0, stream>>>(opart, Wo, bo, x, out);
    }
}

// Round 14
// 178.806 us; speedup vs baseline: 1.0686x; 1.0668x over previous
//
#include <hip/hip_runtime.h>

typedef __bf16 bf16_t;
typedef __bf16 bf16x8 __attribute__((ext_vector_type(8)));
typedef float  f32x4  __attribute__((ext_vector_type(4)));
typedef unsigned u32x4 __attribute__((ext_vector_type(4)));

#define MFMA16(a, b, c) __builtin_amdgcn_mfma_f32_16x16x32_bf16((a), (b), (c), 0, 0, 0)

__device__ __forceinline__ float exp2_f(float x) { return __builtin_amdgcn_exp2f(x); }

union BPack { bf16_t h[2]; unsigned u; };

constexpr int Bn = 4, Cc = 128, Nn = 4096, NH = 4, DK = 32;
// fold 1/sqrt(32) * log2(e) into stored Q so MFMA emits exp2-domain logits
constexpr float QSCALE = 0.176776695f * 1.44269504f;

// ---------------------------------------------------------------------------
// K1: fused transpose + QKV projection.
//   v -> vt_s[bh][d][J] transposed; stored value at J is V[p(J)],
//   p(J)=(J&~31)+((J&31)>>1)+((J&1)*16)  (matches MFMA A/B k-slot interleave)
// ---------------------------------------------------------------------------
__global__ __launch_bounds__(256) void k_qkv(const float* __restrict__ x,
                                             const float* __restrict__ Wp,
                                             const float* __restrict__ bp,
                                             bf16_t* __restrict__ q_s,
                                             bf16_t* __restrict__ k_s,
                                             bf16_t* __restrict__ vt_s)
{
    __shared__ __attribute__((aligned(16))) char smem[40960]; // xs 16KB + wp 24KB
    const int n0 = blockIdx.x * 64;
    const int b  = blockIdx.y;
    const int h  = blockIdx.z;
    const int t  = threadIdx.x;
    const int w = t >> 6, lane = t & 63, a = lane & 15, g = lane >> 4;

    const float* xb = x + (size_t)b * Cc * Nn;
    #pragma unroll
    for (int it = 0; it < 16; ++it) {
        int c = ((t >> 6) + it * 4) * 2;
        int n = t & 63;
        BPack p;
        p.h[0] = (bf16_t)xb[(size_t)c * Nn + n0 + n];
        p.h[1] = (bf16_t)xb[(size_t)(c + 1) * Nn + n0 + n];
        unsigned byte = n * 256 + ((unsigned)(c * 2) ^ ((n & 7) << 4));
        *(unsigned*)(smem + byte) = p.u;
    }
    const float* wpg = Wp + (size_t)h * 96 * Cc;
    #pragma unroll
    for (int it = 0; it < 24; ++it) {
        int idx = t + it * 256;
        int row = idx >> 6;
        int col = (idx & 63) * 2;
        BPack p;
        p.h[0] = (bf16_t)wpg[row * Cc + col];
        p.h[1] = (bf16_t)wpg[row * Cc + col + 1];
        unsigned byte = 16384 + row * 256 + ((unsigned)(col * 2) ^ ((row & 7) << 4));
        *(unsigned*)(smem + byte) = p.u;
    }
    __syncthreads();

    f32x4 acc[6] = {};
    #pragma unroll
    for (int kc = 0; kc < 4; ++kc) {
        int cb = (kc * 32 + g * 8) * 2;
        int rowA = w * 16 + a;
        bf16x8 af = *(const bf16x8*)(smem + rowA * 256 + (cb ^ ((rowA & 7) << 4)));
        #pragma unroll
        for (int pt = 0; pt < 6; ++pt) {
            int rowB = pt * 16 + a;
            bf16x8 bfr = *(const bf16x8*)(smem + 16384 + rowB * 256 + (cb ^ ((rowB & 7) << 4)));
            acc[pt] = MFMA16(af, bfr, acc[pt]);
        }
    }

    const int bh = b * NH + h;
    #pragma unroll
    for (int pt = 0; pt < 4; ++pt) {
        const int which = pt >> 1;
        const int d = (pt & 1) * 16 + a;
        const float bias = bp[h * 96 + which * 32 + d];
        bf16_t* dst = which ? k_s : q_s;
        const float sc = which ? 1.0f : QSCALE;
        #pragma unroll
        for (int r = 0; r < 4; ++r) {
            int n = n0 + w * 16 + g * 4 + r;
            dst[((size_t)bh * Nn + n) * DK + d] = (bf16_t)((acc[pt][r] + bias) * sc);
        }
    }
    __syncthreads();
    bf16_t* vt_l = (bf16_t*)smem;
    #pragma unroll
    for (int pt = 4; pt < 6; ++pt) {
        const int d = (pt & 1) * 16 + a;
        const float bias = bp[h * 96 + 64 + d];
        #pragma unroll
        for (int r = 0; r < 4; ++r) {
            int nl = w * 16 + g * 4 + r;
            vt_l[d * 72 + nl] = (bf16_t)(acc[pt][r] + bias);
        }
    }
    __syncthreads();
    #pragma unroll
    for (int it = 0; it < 8; ++it) {
        int idx = t + it * 256;
        int d = idx >> 6, n = idx & 63;
        int m = n & 31;
        int col = ((m & 15) << 1) | (m >> 4);
        int jj = (n & 32) | col;
        vt_s[((size_t)bh * DK + d) * Nn + n0 + jj] = vt_l[d * 72 + n];
    }
}

// ---------------------------------------------------------------------------
// K2: partial column sums. S_part[is][bh][j] = sum_{i in split is} 2^t[i,j].
// R11-proven widened structure (exact): wave owns 32 j (2 K-fragments),
// 32 i/iter (2 qf loads, 4 MFMA, 16 exp2, 4 acc sets). No manual prefetch,
// no min-waves clause, no XCD swizzle (R13 showed it neutral-to-negative).
// Grid: 16bh x 32jc x 4isplit = 2048 blocks.
// ---------------------------------------------------------------------------
__global__ __launch_bounds__(256) void k_stats(const bf16_t* __restrict__ q_s,
                                               const bf16_t* __restrict__ k_s,
                                               float* __restrict__ S_part)
{
    const int bx = blockIdx.x;
    const int is = bx & 3;
    const int jc = (bx >> 2) & 31;
    const int bh = bx >> 7;
    const int t = threadIdx.x, w = t >> 6, lane = t & 63, a = lane & 15, g = lane >> 4;
    const bf16_t* Q = q_s + (size_t)bh * Nn * DK;
    const bf16_t* K = k_s + (size_t)bh * Nn * DK;
    const int jb = jc * 128 + w * 32;
    bf16x8 kf0 = *(const bf16x8*)(K + (jb + a) * DK + g * 8);
    bf16x8 kf1 = *(const bf16x8*)(K + (jb + 16 + a) * DK + g * 8);
    f32x4 l0 = {}, l1 = {}, l2 = {}, l3 = {};
    const int ilo = is * (Nn / 4);
    #pragma unroll 2
    for (int i0 = ilo; i0 < ilo + Nn / 4; i0 += 32) {
        bf16x8 qfA = *(const bf16x8*)(Q + (i0 + a) * DK + g * 8);
        bf16x8 qfB = *(const bf16x8*)(Q + (i0 + 16 + a) * DK + g * 8);
        f32x4 z = {};
        f32x4 t0 = MFMA16(qfA, kf0, z);
        f32x4 t1 = MFMA16(qfA, kf1, z);
        f32x4 t2 = MFMA16(qfB, kf0, z);
        f32x4 t3 = MFMA16(qfB, kf1, z);
        #pragma unroll
        for (int r = 0; r < 4; ++r) {
            l0[r] += exp2_f(t0[r]);
            l1[r] += exp2_f(t1[r]);
            l2[r] += exp2_f(t2[r]);
            l3[r] += exp2_f(t3[r]);
        }
    }
    l0 += l2;
    l1 += l3;
    float s0 = l0[0] + l0[1] + l0[2] + l0[3];
    float s1 = l1[0] + l1[1] + l1[2] + l1[3];
    s0 += __shfl_xor(s0, 16);
    s0 += __shfl_xor(s0, 32);
    s1 += __shfl_xor(s1, 16);
    s1 += __shfl_xor(s1, 32);
    if (g == 0) {
        float* Sp = S_part + ((size_t)is * 16 + bh) * Nn;
        Sp[jb + a]      = s0;
        Sp[jb + 16 + a] = s1;
    }
}

// ---------------------------------------------------------------------------
// K2b: S_j = sum of 4 partials; scale vt_s rows in place by 1/S[p(J)].
// ---------------------------------------------------------------------------
__global__ __launch_bounds__(256) void k_vscale(const float* __restrict__ S_part,
                                                bf16_t* __restrict__ vt_s)
{
    __shared__ float sinv[512];
    const int Jb = blockIdx.x;   // 0..7, 512 J each
    const int bh = blockIdx.y;   // 0..15
    const int t = threadIdx.x;
    if (t < 128) {
        #pragma unroll
        for (int k2 = 0; k2 < 4; ++k2) {
            int Jl = t * 4 + k2;
            int m = Jl & 31;
            int pJ = (Jl & ~31) | (m >> 1) | ((m & 1) << 4);  // inverse of k_qkv's store permutation
            int J = Jb * 512 + pJ;
            float s = 0.f;
            #pragma unroll
            for (int is = 0; is < 4; ++is)
                s += S_part[((size_t)is * 16 + bh) * Nn + J];
            sinv[Jl] = 1.0f / s;
        }
    }
    __syncthreads();
    bf16_t* vrow = vt_s + (size_t)bh * DK * Nn;
    #pragma unroll
    for (int it = 0; it < 8; ++it) {
        int idx = t + it * 256;
        int d = idx >> 6, Jg = (idx & 63) * 8;
        bf16_t* p = vrow + (size_t)d * Nn + Jb * 512 + Jg;
        bf16x8 v = *(const bf16x8*)p;
        #pragma unroll
        for (int k2 = 0; k2 < 8; ++k2) v[k2] = (bf16_t)((float)v[k2] * sinv[Jg + k2]);
        *(bf16x8*)p = v;
    }
}

// ---------------------------------------------------------------------------
// K3: O[i,d] = sum_j 2^t[i,j] * V'[j,d], j-split into bf16 pair-packed
// partials. EXACT R11 champion body (56.4 us): swapped QK^T keeps P in
// registers; wave holds 64 i (4 Q-fragments); 4 kf/vf loads per 32-j chunk
// feed 16 MFMA + 32 exp2 with depth-1 named prefetch. No setprio (R12 null),
// no XCD swizzle (R13 negative), no depth-2 (R13 null).
// ---------------------------------------------------------------------------
template<int JSPAN>
__global__ __launch_bounds__(256, 4) void k_attn(const bf16_t* __restrict__ q_s,
                                                 const bf16_t* __restrict__ k_s,
                                                 const bf16_t* __restrict__ vt_s,
                                                 unsigned* __restrict__ opart)
{
    constexpr int NJS = Nn / JSPAN;
    const int bx = blockIdx.x;
    const int js = bx % NJS;
    const int ic = (bx / NJS) & 15;
    const int bh = bx / (NJS * 16);
    const int b = bh >> 2, h = bh & 3;
    const int t = threadIdx.x, w = t >> 6, lane = t & 63, a = lane & 15, g = lane >> 4;
    const int ib = ic * 256 + w * 64;
    const bf16_t* Q  = q_s  + (size_t)bh * Nn * DK;
    const bf16_t* K  = k_s  + (size_t)bh * Nn * DK;
    const bf16_t* Vt = vt_s + (size_t)bh * DK * Nn;
    bf16x8 qf[4];
    #pragma unroll
    for (int it = 0; it < 4; ++it)
        qf[it] = *(const bf16x8*)(Q + (size_t)(ib + it * 16 + a) * DK + g * 8);
    f32x4 o0[4] = {}, o1[4] = {};
    auto compute = [&](bf16x8 ck0, bf16x8 ck1, bf16x8 cv0, bf16x8 cv1) {
        f32x4 z = {};
        #pragma unroll
        for (int it = 0; it < 4; ++it) {
            f32x4 s0 = MFMA16(ck0, qf[it], z);   // S^T: rows=j-tile0, cols=i
            f32x4 s1 = MFMA16(ck1, qf[it], z);   // S^T: rows=j-tile1, cols=i
            bf16x8 pa;
            #pragma unroll
            for (int r = 0; r < 4; ++r) {
                pa[2 * r]     = (bf16_t)exp2_f(s0[r]);
                pa[2 * r + 1] = (bf16_t)exp2_f(s1[r]);
            }
            o0[it] = MFMA16(pa, cv0, o0[it]);
            o1[it] = MFMA16(pa, cv1, o1[it]);
        }
    };
    const int jlo = js * JSPAN;
    bf16x8 kf0 = *(const bf16x8*)(K + (size_t)(jlo + a) * DK + g * 8);
    bf16x8 kf1 = *(const bf16x8*)(K + (size_t)(jlo + 16 + a) * DK + g * 8);
    bf16x8 vf0 = *(const bf16x8*)(Vt + (size_t)a * Nn + jlo + g * 8);
    bf16x8 vf1 = *(const bf16x8*)(Vt + (size_t)(16 + a) * Nn + jlo + g * 8);
    #pragma unroll 2
    for (int j0 = jlo; j0 < jlo + JSPAN - 32; j0 += 32) {
        bf16x8 ck0 = kf0, ck1 = kf1, cv0 = vf0, cv1 = vf1;
        kf0 = *(const bf16x8*)(K + (size_t)(j0 + 32 + a) * DK + g * 8);
        kf1 = *(const bf16x8*)(K + (size_t)(j0 + 48 + a) * DK + g * 8);
        vf0 = *(const bf16x8*)(Vt + (size_t)a * Nn + j0 + 32 + g * 8);
        vf1 = *(const bf16x8*)(Vt + (size_t)(16 + a) * Nn + j0 + 32 + g * 8);
        compute(ck0, ck1, cv0, cv1);
    }
    compute(kf0, kf1, vf0, vf1);

    // pair-packed store: word (h*16 + a) of row n holds channels (h*32+a, h*32+16+a)
    unsigned* Ob = opart + ((size_t)(js * Bn + b) * Nn) * 64 + h * 16 + a;
    #pragma unroll
    for (int it = 0; it < 4; ++it) {
        #pragma unroll
        for (int r = 0; r < 4; ++r) {
            int n = ib + it * 16 + g * 4 + r;
            BPack p;
            p.h[0] = (bf16_t)o0[it][r];
            p.h[1] = (bf16_t)o1[it][r];
            Ob[(size_t)n * 64] = p.u;
        }
    }
}

// ---------------------------------------------------------------------------
// K4: out[b][c][n] = ((sum_js opart) @ Wo^T)[n][c] + bo[c] + x[b][c][n]
// opart is u32 pair-packed bf16. NJS templated (full unroll). NEW: grid
// split along output-channel halves (blockIdx.z = ch): each block stages
// only its 64 rows of Wo, computes 4 c-tiles, transposes [64][65] — work
// per block halves, grid 256->512 = 2 blocks/CU (was 1, the pipeline's
// worst occupancy).
// ---------------------------------------------------------------------------
template<int NJS>
__global__ __launch_bounds__(256) void k_out(const unsigned* __restrict__ opart,
                                             const float* __restrict__ Wo,
                                             const float* __restrict__ bo,
                                             const float* __restrict__ x,
                                             float* __restrict__ out)
{
    __shared__ __attribute__((aligned(16))) char smem[16896]; // Wo-half bf16 16KB, then out_t [64][65] f32 (16.6KB) overlaid
    const int n0 = blockIdx.x * 64;
    const int b = blockIdx.y;
    const int ch = blockIdx.z;            // channel half: c in [ch*64, ch*64+64)
    const int t = threadIdx.x, w = t >> 6, lane = t & 63, a = lane & 15, g = lane >> 4;
    const float* WoH = Wo + (size_t)ch * 64 * 128;
    #pragma unroll
    for (int it = 0; it < 16; ++it) {
        int idx = t + it * 256;
        int row = idx >> 6;               // 0..63 local c-row
        int col = (idx & 63) * 2;
        BPack p;
        p.h[0] = (bf16_t)WoH[row * 128 + col];
        p.h[1] = (bf16_t)WoH[row * 128 + col + 1];
        unsigned byte = row * 256 + ((unsigned)(col * 2) ^ ((row & 7) << 4));
        *(unsigned*)(smem + byte) = p.u;
    }
    __syncthreads();
    const size_t OSTR32 = (size_t)Bn * Nn * 64;
    const unsigned* Ob = opart + ((size_t)b * Nn + n0 + w * 16 + a) * 64;
    const unsigned hi = (g >= 2);
    const int wsub = (g & 1) * 8;
    f32x4 acc[4] = {};
    #pragma unroll
    for (int kc = 0; kc < 4; ++kc) {
        float s[8] = {};
        #pragma unroll
        for (int js = 0; js < NJS; ++js) {
            const unsigned* pp = Ob + (size_t)js * OSTR32 + kc * 16 + wsub;
            u32x4 v0 = *(const u32x4*)pp;
            u32x4 v1 = *(const u32x4*)(pp + 4);
            #pragma unroll
            for (int k2 = 0; k2 < 4; ++k2) {
                s[k2]     += __uint_as_float(hi ? (v0[k2] & 0xffff0000u) : (v0[k2] << 16));
                s[k2 + 4] += __uint_as_float(hi ? (v1[k2] & 0xffff0000u) : (v1[k2] << 16));
            }
        }
        bf16x8 af;
        #pragma unroll
        for (int k2 = 0; k2 < 8; ++k2) af[k2] = (bf16_t)s[k2];
        int cb = (kc * 32 + g * 8) * 2;
        #pragma unroll
        for (int ct = 0; ct < 4; ++ct) {
            int rowB = ct * 16 + a;       // local c-row
            bf16x8 bfr = *(const bf16x8*)(smem + rowB * 256 + (cb ^ ((rowB & 7) << 4)));
            acc[ct] = MFMA16(af, bfr, acc[ct]);
        }
    }
    __syncthreads();
    float* out_t = (float*)smem;   // [64][65]
    #pragma unroll
    for (int ct = 0; ct < 4; ++ct) {
        int c = ct * 16 + a;              // local c-row 0..63
        #pragma unroll
        for (int r = 0; r < 4; ++r) {
            out_t[c * 65 + w * 16 + g * 4 + r] = acc[ct][r];
        }
    }
    __syncthreads();
    const float* xb = x + (size_t)b * Cc * Nn;
    #pragma unroll
    for (int it = 0; it < 16; ++it) {
        int idx = t + it * 256;
        int cl = idx >> 6, n = idx & 63;  // local c-row, n within tile
        int c = ch * 64 + cl;
        out[((size_t)b * Cc + c) * Nn + n0 + n] = out_t[cl * 65 + n] + xb[(size_t)c * Nn + n0 + n] + bo[c];
    }
}

extern "C" void kernel_launch(void* const* d_in, const int* in_sizes, int n_in,
                              void* d_out, int out_size, void* d_ws, size_t ws_size,
                              hipStream_t stream)
{
    const float* x  = (const float*)d_in[0];
    const float* Wp = (const float*)d_in[1];
    const float* bp = (const float*)d_in[2];
    const float* Wo = (const float*)d_in[3];
    const float* bo = (const float*)d_in[4];
    float* out = (float*)d_out;

    char* ws = (char*)d_ws;
    bf16_t*  q_s   = (bf16_t*)(ws);                 // 4 MB
    bf16_t*  k_s   = (bf16_t*)(ws + (4  << 20));    // 4 MB
    bf16_t*  vt_s  = (bf16_t*)(ws + (8  << 20));    // 4 MB
    float*   S_part= (float*) (ws + (12 << 20));    // 1 MB (4 splits x 16bh x 4096 f32)
    unsigned* opart= (unsigned*)(ws + (13 << 20));  // NJS x 4 MB (bf16 pair-packed)

    const size_t base = 13ull << 20;
    const size_t plane = 4ull << 20;
    int NJS = 1;
    if (ws_size >= base + 4 * plane) NJS = 4;
    else if (ws_size >= base + 2 * plane) NJS = 2;

    k_qkv   <<<dim3(Nn / 64, Bn, NH),   256, 0, stream>>>(x, Wp, bp, q_s, k_s, vt_s);
    k_stats <<<16 * 32 * 4,             256, 0, stream>>>(q_s, k_s, S_part);
    k_vscale<<<dim3(8, 16),             256, 0, stream>>>(S_part, vt_s);
    if (NJS == 4) {
        k_attn<1024><<<16 * 16 * 4, 256, 0, stream>>>(q_s, k_s, vt_s, opart);
        k_out<4><<<dim3(Nn / 64, Bn, 2), 256, 0, stream>>>(opart, Wo, bo, x, out);
    } else if (NJS == 2) {
        k_attn<2048><<<16 * 16 * 2, 256, 0, stream>>>(q_s, k_s, vt_s, opart);
        k_out<2><<<dim3(Nn / 64, Bn, 2), 256, 0, stream>>>(opart, Wo, bo, x, out);
    } else {
        k_attn<4096><<<16 * 16 * 1, 256, 0, stream>>>(q_s, k_s, vt_s, opart);
        k_out<1><<<dim3(Nn / 64, Bn, 2), 256, 0, stream>>>(opart, Wo, bo, x, out);
    }
}

// Round 15
// 175.977 us; speedup vs baseline: 1.0858x; 1.0161x over previous
//
#include <hip/hip_runtime.h>

typedef __bf16 bf16_t;
typedef __bf16 bf16x8 __attribute__((ext_vector_type(8)));
typedef float  f32x4  __attribute__((ext_vector_type(4)));
typedef unsigned u32x4 __attribute__((ext_vector_type(4)));

#define MFMA16(a, b, c) __builtin_amdgcn_mfma_f32_16x16x32_bf16((a), (b), (c), 0, 0, 0)

__device__ __forceinline__ float exp2_f(float x) { return __builtin_amdgcn_exp2f(x); }

union BPack { bf16_t h[2]; unsigned u; };

constexpr int Bn = 4, Cc = 128, Nn = 4096, NH = 4, DK = 32;
// fold 1/sqrt(32) * log2(e) into stored Q so MFMA emits exp2-domain logits
constexpr float QSCALE = 0.176776695f * 1.44269504f;

// ---------------------------------------------------------------------------
// K1: fused transpose + QKV projection.
//   v -> vt_s[bh][d][J] transposed; stored value at J is V[p(J)],
//   p(J)=(J&~31)+((J&31)>>1)+((J&1)*16)  (matches MFMA A/B k-slot interleave)
// ---------------------------------------------------------------------------
__global__ __launch_bounds__(256) void k_qkv(const float* __restrict__ x,
                                             const float* __restrict__ Wp,
                                             const float* __restrict__ bp,
                                             bf16_t* __restrict__ q_s,
                                             bf16_t* __restrict__ k_s,
                                             bf16_t* __restrict__ vt_s)
{
    __shared__ __attribute__((aligned(16))) char smem[40960]; // xs 16KB + wp 24KB
    const int n0 = blockIdx.x * 64;
    const int b  = blockIdx.y;
    const int h  = blockIdx.z;
    const int t  = threadIdx.x;
    const int w = t >> 6, lane = t & 63, a = lane & 15, g = lane >> 4;

    const float* xb = x + (size_t)b * Cc * Nn;
    #pragma unroll
    for (int it = 0; it < 16; ++it) {
        int c = ((t >> 6) + it * 4) * 2;
        int n = t & 63;
        BPack p;
        p.h[0] = (bf16_t)xb[(size_t)c * Nn + n0 + n];
        p.h[1] = (bf16_t)xb[(size_t)(c + 1) * Nn + n0 + n];
        unsigned byte = n * 256 + ((unsigned)(c * 2) ^ ((n & 7) << 4));
        *(unsigned*)(smem + byte) = p.u;
    }
    const float* wpg = Wp + (size_t)h * 96 * Cc;
    #pragma unroll
    for (int it = 0; it < 24; ++it) {
        int idx = t + it * 256;
        int row = idx >> 6;
        int col = (idx & 63) * 2;
        BPack p;
        p.h[0] = (bf16_t)wpg[row * Cc + col];
        p.h[1] = (bf16_t)wpg[row * Cc + col + 1];
        unsigned byte = 16384 + row * 256 + ((unsigned)(col * 2) ^ ((row & 7) << 4));
        *(unsigned*)(smem + byte) = p.u;
    }
    __syncthreads();

    f32x4 acc[6] = {};
    #pragma unroll
    for (int kc = 0; kc < 4; ++kc) {
        int cb = (kc * 32 + g * 8) * 2;
        int rowA = w * 16 + a;
        bf16x8 af = *(const bf16x8*)(smem + rowA * 256 + (cb ^ ((rowA & 7) << 4)));
        #pragma unroll
        for (int pt = 0; pt < 6; ++pt) {
            int rowB = pt * 16 + a;
            bf16x8 bfr = *(const bf16x8*)(smem + 16384 + rowB * 256 + (cb ^ ((rowB & 7) << 4)));
            acc[pt] = MFMA16(af, bfr, acc[pt]);
        }
    }

    const int bh = b * NH + h;
    #pragma unroll
    for (int pt = 0; pt < 4; ++pt) {
        const int which = pt >> 1;
        const int d = (pt & 1) * 16 + a;
        const float bias = bp[h * 96 + which * 32 + d];
        bf16_t* dst = which ? k_s : q_s;
        const float sc = which ? 1.0f : QSCALE;
        #pragma unroll
        for (int r = 0; r < 4; ++r) {
            int n = n0 + w * 16 + g * 4 + r;
            dst[((size_t)bh * Nn + n) * DK + d] = (bf16_t)((acc[pt][r] + bias) * sc);
        }
    }
    __syncthreads();
    bf16_t* vt_l = (bf16_t*)smem;
    #pragma unroll
    for (int pt = 4; pt < 6; ++pt) {
        const int d = (pt & 1) * 16 + a;
        const float bias = bp[h * 96 + 64 + d];
        #pragma unroll
        for (int r = 0; r < 4; ++r) {
            int nl = w * 16 + g * 4 + r;
            vt_l[d * 72 + nl] = (bf16_t)(acc[pt][r] + bias);
        }
    }
    __syncthreads();
    #pragma unroll
    for (int it = 0; it < 8; ++it) {
        int idx = t + it * 256;
        int d = idx >> 6, n = idx & 63;
        int m = n & 31;
        int col = ((m & 15) << 1) | (m >> 4);
        int jj = (n & 32) | col;
        vt_s[((size_t)bh * DK + d) * Nn + n0 + jj] = vt_l[d * 72 + n];
    }
}

// ---------------------------------------------------------------------------
// K2: partial column sums. S_part[is][bh][j] = sum_{i in split is} 2^t[i,j].
// R15: k_attn's PROVEN loop shape ported — wave holds 64 j (4 K-fragments,
// like k_attn's qf[4]); streams i in 32-chunks with depth-1 NAMED prefetch;
// per iter 2 loads -> 8 MFMA + 32 exp2; acc merged to 4 sets (A/B summed at
// the exp2-add, halving acc regs vs R6's 8-set blowup); #pragma unroll 1
// denies the software-pipeliner the unroll space that caused R6/R7 spills.
// Grid: 16bh x 16jc x 4is = 1024 blocks (same as k_attn).
// ---------------------------------------------------------------------------
__global__ __launch_bounds__(256, 4) void k_stats(const bf16_t* __restrict__ q_s,
                                                  const bf16_t* __restrict__ k_s,
                                                  float* __restrict__ S_part)
{
    const int bx = blockIdx.x;
    const int is = bx & 3;
    const int jc = (bx >> 2) & 15;
    const int bh = bx >> 6;
    const int t = threadIdx.x, w = t >> 6, lane = t & 63, a = lane & 15, g = lane >> 4;
    const bf16_t* Q = q_s + (size_t)bh * Nn * DK;
    const bf16_t* K = k_s + (size_t)bh * Nn * DK;
    const int jb = jc * 256 + w * 64;
    bf16x8 kf[4];
    #pragma unroll
    for (int it = 0; it < 4; ++it)
        kf[it] = *(const bf16x8*)(K + (size_t)(jb + it * 16 + a) * DK + g * 8);
    f32x4 l[4] = {};
    auto step = [&](bf16x8 cA, bf16x8 cB) {
        f32x4 z = {};
        #pragma unroll
        for (int it = 0; it < 4; ++it) {
            f32x4 tA = MFMA16(cA, kf[it], z);
            f32x4 tB = MFMA16(cB, kf[it], z);
            #pragma unroll
            for (int r = 0; r < 4; ++r) {
                l[it][r] += exp2_f(tA[r]) + exp2_f(tB[r]);
            }
        }
    };
    const int ilo = is * (Nn / 4);
    bf16x8 qA = *(const bf16x8*)(Q + (size_t)(ilo + a) * DK + g * 8);
    bf16x8 qB = *(const bf16x8*)(Q + (size_t)(ilo + 16 + a) * DK + g * 8);
    #pragma unroll 1
    for (int i0 = ilo; i0 < ilo + Nn / 4 - 32; i0 += 32) {
        bf16x8 cA = qA, cB = qB;
        qA = *(const bf16x8*)(Q + (size_t)(i0 + 32 + a) * DK + g * 8);
        qB = *(const bf16x8*)(Q + (size_t)(i0 + 48 + a) * DK + g * 8);
        step(cA, cB);
    }
    step(qA, qB);
    float* Sp = S_part + ((size_t)is * 16 + bh) * Nn;
    #pragma unroll
    for (int it = 0; it < 4; ++it) {
        float s = l[it][0] + l[it][1] + l[it][2] + l[it][3];
        s += __shfl_xor(s, 16);
        s += __shfl_xor(s, 32);
        if (g == 0) Sp[jb + it * 16 + a] = s;
    }
}

// ---------------------------------------------------------------------------
// K2b: S_j = sum of 4 partials; scale vt_s rows in place by 1/S[p(J)].
// ---------------------------------------------------------------------------
__global__ __launch_bounds__(256) void k_vscale(const float* __restrict__ S_part,
                                                bf16_t* __restrict__ vt_s)
{
    __shared__ float sinv[512];
    const int Jb = blockIdx.x;   // 0..7, 512 J each
    const int bh = blockIdx.y;   // 0..15
    const int t = threadIdx.x;
    if (t < 128) {
        #pragma unroll
        for (int k2 = 0; k2 < 4; ++k2) {
            int Jl = t * 4 + k2;
            int m = Jl & 31;
            int pJ = (Jl & ~31) | (m >> 1) | ((m & 1) << 4);  // inverse of k_qkv's store permutation
            int J = Jb * 512 + pJ;
            float s = 0.f;
            #pragma unroll
            for (int is = 0; is < 4; ++is)
                s += S_part[((size_t)is * 16 + bh) * Nn + J];
            sinv[Jl] = 1.0f / s;
        }
    }
    __syncthreads();
    bf16_t* vrow = vt_s + (size_t)bh * DK * Nn;
    #pragma unroll
    for (int it = 0; it < 8; ++it) {
        int idx = t + it * 256;
        int d = idx >> 6, Jg = (idx & 63) * 8;
        bf16_t* p = vrow + (size_t)d * Nn + Jb * 512 + Jg;
        bf16x8 v = *(const bf16x8*)p;
        #pragma unroll
        for (int k2 = 0; k2 < 8; ++k2) v[k2] = (bf16_t)((float)v[k2] * sinv[Jg + k2]);
        *(bf16x8*)p = v;
    }
}

// ---------------------------------------------------------------------------
// K3: O[i,d] = sum_j 2^t[i,j] * V'[j,d], j-split into bf16 pair-packed
// partials. EXACT R11 champion body (56.4 us): swapped QK^T keeps P in
// registers; wave holds 64 i (4 Q-fragments); 4 kf/vf loads per 32-j chunk
// feed 16 MFMA + 32 exp2 with depth-1 named prefetch. No setprio (R12 null),
// no XCD swizzle (R13 negative), no depth-2 (R13 null).
// ---------------------------------------------------------------------------
template<int JSPAN>
__global__ __launch_bounds__(256, 4) void k_attn(const bf16_t* __restrict__ q_s,
                                                 const bf16_t* __restrict__ k_s,
                                                 const bf16_t* __restrict__ vt_s,
                                                 unsigned* __restrict__ opart)
{
    constexpr int NJS = Nn / JSPAN;
    const int bx = blockIdx.x;
    const int js = bx % NJS;
    const int ic = (bx / NJS) & 15;
    const int bh = bx / (NJS * 16);
    const int b = bh >> 2, h = bh & 3;
    const int t = threadIdx.x, w = t >> 6, lane = t & 63, a = lane & 15, g = lane >> 4;
    const int ib = ic * 256 + w * 64;
    const bf16_t* Q  = q_s  + (size_t)bh * Nn * DK;
    const bf16_t* K  = k_s  + (size_t)bh * Nn * DK;
    const bf16_t* Vt = vt_s + (size_t)bh * DK * Nn;
    bf16x8 qf[4];
    #pragma unroll
    for (int it = 0; it < 4; ++it)
        qf[it] = *(const bf16x8*)(Q + (size_t)(ib + it * 16 + a) * DK + g * 8);
    f32x4 o0[4] = {}, o1[4] = {};
    auto compute = [&](bf16x8 ck0, bf16x8 ck1, bf16x8 cv0, bf16x8 cv1) {
        f32x4 z = {};
        #pragma unroll
        for (int it = 0; it < 4; ++it) {
            f32x4 s0 = MFMA16(ck0, qf[it], z);   // S^T: rows=j-tile0, cols=i
            f32x4 s1 = MFMA16(ck1, qf[it], z);   // S^T: rows=j-tile1, cols=i
            bf16x8 pa;
            #pragma unroll
            for (int r = 0; r < 4; ++r) {
                pa[2 * r]     = (bf16_t)exp2_f(s0[r]);
                pa[2 * r + 1] = (bf16_t)exp2_f(s1[r]);
            }
            o0[it] = MFMA16(pa, cv0, o0[it]);
            o1[it] = MFMA16(pa, cv1, o1[it]);
        }
    };
    const int jlo = js * JSPAN;
    bf16x8 kf0 = *(const bf16x8*)(K + (size_t)(jlo + a) * DK + g * 8);
    bf16x8 kf1 = *(const bf16x8*)(K + (size_t)(jlo + 16 + a) * DK + g * 8);
    bf16x8 vf0 = *(const bf16x8*)(Vt + (size_t)a * Nn + jlo + g * 8);
    bf16x8 vf1 = *(const bf16x8*)(Vt + (size_t)(16 + a) * Nn + jlo + g * 8);
    #pragma unroll 2
    for (int j0 = jlo; j0 < jlo + JSPAN - 32; j0 += 32) {
        bf16x8 ck0 = kf0, ck1 = kf1, cv0 = vf0, cv1 = vf1;
        kf0 = *(const bf16x8*)(K + (size_t)(j0 + 32 + a) * DK + g * 8);
        kf1 = *(const bf16x8*)(K + (size_t)(j0 + 48 + a) * DK + g * 8);
        vf0 = *(const bf16x8*)(Vt + (size_t)a * Nn + j0 + 32 + g * 8);
        vf1 = *(const bf16x8*)(Vt + (size_t)(16 + a) * Nn + j0 + 32 + g * 8);
        compute(ck0, ck1, cv0, cv1);
    }
    compute(kf0, kf1, vf0, vf1);

    // pair-packed store: word (h*16 + a) of row n holds channels (h*32+a, h*32+16+a)
    unsigned* Ob = opart + ((size_t)(js * Bn + b) * Nn) * 64 + h * 16 + a;
    #pragma unroll
    for (int it = 0; it < 4; ++it) {
        #pragma unroll
        for (int r = 0; r < 4; ++r) {
            int n = ib + it * 16 + g * 4 + r;
            BPack p;
            p.h[0] = (bf16_t)o0[it][r];
            p.h[1] = (bf16_t)o1[it][r];
            Ob[(size_t)n * 64] = p.u;
        }
    }
}

// ---------------------------------------------------------------------------
// K4: out[b][c][n] = ((sum_js opart) @ Wo^T)[n][c] + bo[c] + x[b][c][n]
// opart is u32 pair-packed bf16. NJS templated (full unroll). Grid split
// along output-channel halves (blockIdx.z = ch): work per block halves,
// grid 512 = 2 blocks/CU (R14: -8 us on total).
// ---------------------------------------------------------------------------
template<int NJS>
__global__ __launch_bounds__(256) void k_out(const unsigned* __restrict__ opart,
                                             const float* __restrict__ Wo,
                                             const float* __restrict__ bo,
                                             const float* __restrict__ x,
                                             float* __restrict__ out)
{
    __shared__ __attribute__((aligned(16))) char smem[16896]; // Wo-half bf16 16KB, then out_t [64][65] f32 overlaid
    const int n0 = blockIdx.x * 64;
    const int b = blockIdx.y;
    const int ch = blockIdx.z;            // channel half: c in [ch*64, ch*64+64)
    const int t = threadIdx.x, w = t >> 6, lane = t & 63, a = lane & 15, g = lane >> 4;
    const float* WoH = Wo + (size_t)ch * 64 * 128;
    #pragma unroll
    for (int it = 0; it < 16; ++it) {
        int idx = t + it * 256;
        int row = idx >> 6;               // 0..63 local c-row
        int col = (idx & 63) * 2;
        BPack p;
        p.h[0] = (bf16_t)WoH[row * 128 + col];
        p.h[1] = (bf16_t)WoH[row * 128 + col + 1];
        unsigned byte = row * 256 + ((unsigned)(col * 2) ^ ((row & 7) << 4));
        *(unsigned*)(smem + byte) = p.u;
    }
    __syncthreads();
    const size_t OSTR32 = (size_t)Bn * Nn * 64;
    const unsigned* Ob = opart + ((size_t)b * Nn + n0 + w * 16 + a) * 64;
    const unsigned hi = (g >= 2);
    const int wsub = (g & 1) * 8;
    f32x4 acc[4] = {};
    #pragma unroll
    for (int kc = 0; kc < 4; ++kc) {
        float s[8] = {};
        #pragma unroll
        for (int js = 0; js < NJS; ++js) {
            const unsigned* pp = Ob + (size_t)js * OSTR32 + kc * 16 + wsub;
            u32x4 v0 = *(const u32x4*)pp;
            u32x4 v1 = *(const u32x4*)(pp + 4);
            #pragma unroll
            for (int k2 = 0; k2 < 4; ++k2) {
                s[k2]     += __uint_as_float(hi ? (v0[k2] & 0xffff0000u) : (v0[k2] << 16));
                s[k2 + 4] += __uint_as_float(hi ? (v1[k2] & 0xffff0000u) : (v1[k2] << 16));
            }
        }
        bf16x8 af;
        #pragma unroll
        for (int k2 = 0; k2 < 8; ++k2) af[k2] = (bf16_t)s[k2];
        int cb = (kc * 32 + g * 8) * 2;
        #pragma unroll
        for (int ct = 0; ct < 4; ++ct) {
            int rowB = ct * 16 + a;       // local c-row
            bf16x8 bfr = *(const bf16x8*)(smem + rowB * 256 + (cb ^ ((rowB & 7) << 4)));
            acc[ct] = MFMA16(af, bfr, acc[ct]);
        }
    }
    __syncthreads();
    float* out_t = (float*)smem;   // [64][65]
    #pragma unroll
    for (int ct = 0; ct < 4; ++ct) {
        int c = ct * 16 + a;              // local c-row 0..63
        #pragma unroll
        for (int r = 0; r < 4; ++r) {
            out_t[c * 65 + w * 16 + g * 4 + r] = acc[ct][r];
        }
    }
    __syncthreads();
    const float* xb = x + (size_t)b * Cc * Nn;
    #pragma unroll
    for (int it = 0; it < 16; ++it) {
        int idx = t + it * 256;
        int cl = idx >> 6, n = idx & 63;  // local c-row, n within tile
        int c = ch * 64 + cl;
        out[((size_t)b * Cc + c) * Nn + n0 + n] = out_t[cl * 65 + n] + xb[(size_t)c * Nn + n0 + n] + bo[c];
    }
}

extern "C" void kernel_launch(void* const* d_in, const int* in_sizes, int n_in,
                              void* d_out, int out_size, void* d_ws, size_t ws_size,
                              hipStream_t stream)
{
    const float* x  = (const float*)d_in[0];
    const float* Wp = (const float*)d_in[1];
    const float* bp = (const float*)d_in[2];
    const float* Wo = (const float*)d_in[3];
    const float* bo = (const float*)d_in[4];
    float* out = (float*)d_out;

    char* ws = (char*)d_ws;
    bf16_t*  q_s   = (bf16_t*)(ws);                 // 4 MB
    bf16_t*  k_s   = (bf16_t*)(ws + (4  << 20));    // 4 MB
    bf16_t*  vt_s  = (bf16_t*)(ws + (8  << 20));    // 4 MB
    float*   S_part= (float*) (ws + (12 << 20));    // 1 MB (4 splits x 16bh x 4096 f32)
    unsigned* opart= (unsigned*)(ws + (13 << 20));  // NJS x 4 MB (bf16 pair-packed)

    const size_t base = 13ull << 20;
    const size_t plane = 4ull << 20;
    int NJS = 1;
    if (ws_size >= base + 4 * plane) NJS = 4;
    else if (ws_size >= base + 2 * plane) NJS = 2;

    k_qkv   <<<dim3(Nn / 64, Bn, NH),   256, 0, stream>>>(x, Wp, bp, q_s, k_s, vt_s);
    k_stats <<<16 * 16 * 4,             256, 0, stream>>>(q_s, k_s, S_part);
    k_vscale<<<dim3(8, 16),             256, 0, stream>>>(S_part, vt_s);
    if (NJS == 4) {
        k_attn<1024><<<16 * 16 * 4, 256, 0, stream>>>(q_s, k_s, vt_s, opart);
        k_out<4><<<dim3(Nn / 64, Bn, 2), 256, 0, stream>>>(opart, Wo, bo, x, out);
    } else if (NJS == 2) {
        k_attn<2048><<<16 * 16 * 2, 256, 0, stream>>>(q_s, k_s, vt_s, opart);
        k_out<2><<<dim3(Nn / 64, Bn, 2), 256, 0, stream>>>(opart, Wo, bo, x, out);
    } else {
        k_attn<4096><<<16 * 16 * 1, 256, 0, stream>>>(q_s, k_s, vt_s, opart);
        k_out<1><<<dim3(Nn / 64, Bn, 2), 256, 0, stream>>>(opart, Wo, bo, x, out);
    }
}